// Round 5
// baseline (2687.839 us; speedup 1.0000x reference)
//
#include <hip/hip_runtime.h>

// TT-LSTM: B=64, T=1024, D=H=256, F=16, R=16, NG=4.
// ws layout (floats):
//   A1ihT [64][256]  @ 0       ([g*16+s][m*16+n], composed g0*g1 for ih)
//   A1hT  [64][256]  @ 16384   (same for hh)
//   C2ih  [64][256]  @ 32768   ([g*16+s][o*16+p], composed g2*g3 for ih)
//   C2h   [64][256]  @ 49152
//   biasS [4][256]   @ 65536   (ih_bias + hh_bias)
//   T2ih  [65536][64]@ 66560   (first-stage ih contraction for all rows)

#define WS_A1I 0
#define WS_A1H 16384
#define WS_C2I 32768
#define WS_C2H 49152
#define WS_BIAS 65536
#define WS_T2 66560

__device__ __forceinline__ float fsig(float x) {
    float e = __builtin_amdgcn_exp2f(-1.442695040888963f * x);
    return __builtin_amdgcn_rcpf(1.0f + e);
}
__device__ __forceinline__ float ftanh_(float x) {
    float e = __builtin_amdgcn_exp2f(2.885390081777926f * x);
    return 1.0f - 2.0f * __builtin_amdgcn_rcpf(1.0f + e);
}

// Barrier draining LDS only (lgkmcnt, incl. ds_add atomics), NOT global
// loads/stores (vmcnt): per-step out-store + T2 prefetch stay in flight.
__device__ __forceinline__ void bar_lds() {
    asm volatile("s_waitcnt lgkmcnt(0)\n\ts_barrier" ::: "memory");
}

// ---------------- K0: compose TT cores ----------------
__global__ void k_compose(const float* __restrict__ g0i, const float* __restrict__ g1i,
                          const float* __restrict__ g2i, const float* __restrict__ g3i,
                          const float* __restrict__ bi,
                          const float* __restrict__ g0h, const float* __restrict__ g1h,
                          const float* __restrict__ g2h, const float* __restrict__ g3h,
                          const float* __restrict__ bh,
                          float* __restrict__ ws) {
    int id = blockIdx.x * 256 + threadIdx.x;
    if (id < 16384) {
        int g = id >> 12, s = (id >> 8) & 15, mn = id & 255;
        int m = mn >> 4, n = mn & 15;
        float aI = 0.f, aH = 0.f;
        for (int r = 0; r < 16; ++r) {
            aI += g0i[(g * 16 + m) * 16 + r] * g1i[((g * 16 + r) * 16 + n) * 16 + s];
            aH += g0h[(g * 16 + m) * 16 + r] * g1h[((g * 16 + r) * 16 + n) * 16 + s];
        }
        ws[WS_A1I + (g * 16 + s) * 256 + mn] = aI;
        ws[WS_A1H + (g * 16 + s) * 256 + mn] = aH;
    } else if (id < 32768) {
        int id2 = id - 16384;
        int g = id2 >> 12, s = (id2 >> 8) & 15, j = id2 & 255;
        int o = j >> 4, p = j & 15;
        float aI = 0.f, aH = 0.f;
        for (int t = 0; t < 16; ++t) {
            aI += g2i[((g * 16 + s) * 16 + o) * 16 + t] * g3i[(g * 16 + t) * 16 + p];
            aH += g2h[((g * 16 + s) * 16 + o) * 16 + t] * g3h[(g * 16 + t) * 16 + p];
        }
        ws[WS_C2I + (g * 16 + s) * 256 + j] = aI;
        ws[WS_C2H + (g * 16 + s) * 256 + j] = aH;
    } else if (id < 33792) {
        int id2 = id - 32768;
        ws[WS_BIAS + id2] = bi[id2] + bh[id2];
    }
}

// ---------------- K1: T2ih = X @ A1ih ----------------
// Both tiles xor-swizzled by (row&15) on the f4-column -> conflict-free reads.
__global__ __launch_bounds__(256, 2) void k_t2ih(const float* __restrict__ x,
                                                 const float* __restrict__ ws,
                                                 float* __restrict__ T2) {
    __shared__ __align__(16) float Xs[64 * 256];
    __shared__ __align__(16) float As[64 * 256];
    const int tid = threadIdx.x;
    const long r0 = (long)blockIdx.x * 64;

    const float4* X4 = (const float4*)(x + r0 * 256);
    const float4* A4 = (const float4*)(ws + WS_A1I);
    float4* Xs4 = (float4*)Xs;
    float4* As4 = (float4*)As;
#pragma unroll
    for (int k = 0; k < 16; ++k) {
        int idx = tid + k * 256;
        int row = idx >> 6, c = idx & 63;
        int sw = (row << 6) | (c ^ (row & 15));
        Xs4[sw] = X4[idx];
        As4[sw] = A4[idx];
    }
    __syncthreads();

    const int ro = tid & 15;
    const int q  = tid >> 4;
    float acc[4][4];
#pragma unroll
    for (int i = 0; i < 4; ++i)
#pragma unroll
        for (int j = 0; j < 4; ++j) acc[i][j] = 0.f;

    for (int mn4 = 0; mn4 < 64; ++mn4) {
        float4 a[4], xv[4];
#pragma unroll
        for (int j = 0; j < 4; ++j) {
            int row = ro * 4 + j;
            a[j] = As4[(row << 6) | (mn4 ^ (row & 15))];
        }
#pragma unroll
        for (int i = 0; i < 4; ++i) {
            int row = q * 4 + i;
            xv[i] = Xs4[(row << 6) | (mn4 ^ (row & 15))];
        }
#pragma unroll
        for (int i = 0; i < 4; ++i)
#pragma unroll
            for (int j = 0; j < 4; ++j)
                acc[i][j] += xv[i].x * a[j].x + xv[i].y * a[j].y +
                             xv[i].z * a[j].z + xv[i].w * a[j].w;
    }
#pragma unroll
    for (int i = 0; i < 4; ++i)
#pragma unroll
        for (int j = 0; j < 4; ++j)
            T2[(r0 + q * 4 + i) * 64 + ro * 4 + j] = acc[i][j];
}

// ---------------- K2: recurrent LSTM ----------------
// 64 blocks x 1024 threads (16 waves, 4/SIMD), 1024 steps, 3 barriers/step.
// Per-thread weights only 49 floats (vs 96 in r3/r4) -> no allocator fight:
//   AB: u=4w+(lane>>4), sub=lane&15, mn-chunk sub*16 -> a1r[16].
//       Reduction over the 16 subs via HW LDS atomic fadd (ds_add_f32),
//       replacing r3's serial 3x shfl_xor chain (~300 cyc critical path).
//   CD: g=w>>2, j=(w&3)*64+lane -> c2h[16]+c2i[16]; gates stored f4-per-j.
// hS stored as transposed float4 slots (slot kk*16+sub = h[16sub+4kk..+3])
// so AB's 16-distinct-address b128 broadcasts are 2-way (free).
__global__ __launch_bounds__(1024, 4) void k_lstm(const float* __restrict__ ws,
                                                  const float* __restrict__ T2,
                                                  float* __restrict__ out) {
    __shared__ __align__(16) float hS[256];
    __shared__ __align__(16) float t2hS[64];
    __shared__ __align__(16) float t2iS[2][64];
    __shared__ __align__(16) float gS[256 * 4];   // [j][g] as float4 per j

    const int tid  = threadIdx.x;
    const int w    = tid >> 6;
    const int lane = tid & 63;
    const int b    = blockIdx.x;

    // ---- AB weights: a1r[16] = A1h[u][sub*16 .. sub*16+16) ----
    const int u   = 4 * w + (lane >> 4);
    const int sub = lane & 15;
    float a1r[16];
    {
        const float4* A1h4 = (const float4*)(ws + WS_A1H);
#pragma unroll
        for (int kk = 0; kk < 4; ++kk) {
            float4 v = A1h4[u * 64 + sub * 4 + kk];
            a1r[4 * kk + 0] = v.x; a1r[4 * kk + 1] = v.y;
            a1r[4 * kk + 2] = v.z; a1r[4 * kk + 3] = v.w;
        }
    }

    // ---- CD weights: gate g, hidden j ----
    const int g = w >> 2;
    const int j = (w & 3) * 64 + lane;
    float c2h[16], c2i[16];
#pragma unroll
    for (int s = 0; s < 16; ++s) {
        c2h[s] = ws[WS_C2H + (16 * g + s) * 256 + j];
        c2i[s] = ws[WS_C2I + (16 * g + s) * 256 + j];
    }
    float bias = ws[WS_BIAS + g * 256 + j];

#pragma unroll
    for (int i = 0; i < 16; ++i)
        asm volatile("" : "+v"(a1r[i]), "+v"(c2h[i]), "+v"(c2i[i]));
    asm volatile("" : "+v"(bias));

    // transposed-f4 write slot for h: word 64*((tid>>2)&3) + 4*(tid>>4) + (tid&3)
    const int hIdx = 64 * ((tid >> 2) & 3) + 4 * (tid >> 4) + (tid & 3);

    float c = 0.f, h_last = 0.f;
    if (tid < 256) hS[tid] = 0.f;                 // zeros are layout-invariant
    if (tid < 64) t2hS[tid] = 0.f;
    const float* T2b = T2 + (long)b * 1024 * 64;
    const float4* T2b4 = (const float4*)T2b;
    float4 preA = make_float4(0.f, 0.f, 0.f, 0.f);
    float4 preB = make_float4(0.f, 0.f, 0.f, 0.f);
    if (tid < 16) {
        ((float4*)t2iS[0])[tid] = T2b4[tid];
        preA = T2b4[16 + tid];                    // T2[t=1]
    }
    bar_lds();

    float* outB = out + (long)b * 1024 * 256;
    const float4* hS4  = (const float4*)hS;
    const float4* th4  = (const float4*)t2hS;

    auto body = [&](int t, float4& preW, float4& preL) {
        // ---- AB: 16-MAC partial, HW atomic reduce into t2hS[u] ----
        float4 s4 = make_float4(0.f, 0.f, 0.f, 0.f);
#pragma unroll
        for (int kk = 0; kk < 4; ++kk) {
            float4 hv = hS4[kk * 16 + sub];       // 2-way, conflict-free
            s4.x += hv.x * a1r[4 * kk + 0];
            s4.y += hv.y * a1r[4 * kk + 1];
            s4.z += hv.z * a1r[4 * kk + 2];
            s4.w += hv.w * a1r[4 * kk + 3];
        }
        atomicAdd(&t2hS[u], (s4.x + s4.y) + (s4.z + s4.w));  // ds_add_f32

        if ((tid < 16) && (t + 2 < 1024))
            preL = T2b4[(t + 2) * 16 + tid];

        bar_lds();  // 1: t2hS complete (atomics drained by lgkmcnt)

        if ((tid < 16) && (t + 1 < 1024))
            ((float4*)t2iS[(t + 1) & 1])[tid] = preW;   // other buffer: no race

        // ---- CD: gate g, hidden j ----
        const float4* ti4 = (const float4*)t2iS[t & 1];
        float acc = bias;
#pragma unroll
        for (int q = 0; q < 4; ++q) {
            float4 th = th4[g * 4 + q];           // wave-uniform broadcast
            float4 ti = ti4[g * 4 + q];
            acc += th.x * c2h[4*q+0] + th.y * c2h[4*q+1] + th.z * c2h[4*q+2] + th.w * c2h[4*q+3]
                 + ti.x * c2i[4*q+0] + ti.y * c2i[4*q+1] + ti.z * c2i[4*q+2] + ti.w * c2i[4*q+3];
        }
        gS[j * 4 + g] = acc;                      // 8-way write, ~free

        bar_lds();  // 2: gS ready

        // ---- cell update: j = tid (waves 0-3); wave 4 re-zeroes t2hS ----
        if (tid < 256) {
            float4 gv = ((const float4*)gS)[tid]; // i,f,g,o in one b128
            float ig = fsig(gv.x), fg = fsig(gv.y), gg = ftanh_(gv.z), og = fsig(gv.w);
            c = fg * c + ig * gg;
            float h = og * ftanh_(c);
            h_last = h;
            outB[t * 256 + tid] = h;              // never drained (bar_lds)
            hS[hIdx] = h;                         // transposed-f4 slot
        } else if (tid < 320) {
            t2hS[tid - 256] = 0.f;                // for next step's atomics
        }

        bar_lds();  // 3: hS/t2hS ready
    };

    for (int t = 0; t < 1024; t += 2) {
        body(t, preA, preB);
        body(t + 1, preB, preA);
    }

    if (tid < 256) {
        out[16777216 + b * 256 + tid] = h_last;
        out[16777216 + 16384 + b * 256 + tid] = c;
    }
}

extern "C" void kernel_launch(void* const* d_in, const int* in_sizes, int n_in,
                              void* d_out, int out_size, void* d_ws, size_t ws_size,
                              hipStream_t stream) {
    const float* x     = (const float*)d_in[0];
    const float* ih_g0 = (const float*)d_in[1];
    const float* ih_g1 = (const float*)d_in[2];
    const float* ih_g2 = (const float*)d_in[3];
    const float* ih_g3 = (const float*)d_in[4];
    const float* ih_b  = (const float*)d_in[5];
    const float* hh_g0 = (const float*)d_in[6];
    const float* hh_g1 = (const float*)d_in[7];
    const float* hh_g2 = (const float*)d_in[8];
    const float* hh_g3 = (const float*)d_in[9];
    const float* hh_b  = (const float*)d_in[10];
    float* out = (float*)d_out;
    float* ws  = (float*)d_ws;

    k_compose<<<132, 256, 0, stream>>>(ih_g0, ih_g1, ih_g2, ih_g3, ih_b,
                                       hh_g0, hh_g1, hh_g2, hh_g3, hh_b, ws);
    k_t2ih<<<1024, 256, 0, stream>>>(x, ws, ws + WS_T2);
    k_lstm<<<64, 1024, 0, stream>>>(ws, ws + WS_T2, out);
}

// Round 6
// 1546.199 us; speedup vs baseline: 1.7384x; 1.7384x over previous
//
#include <hip/hip_runtime.h>

// TT-LSTM: B=64, T=1024, D=H=256, F=16, R=16, NG=4.
// ws layout (floats):
//   A1ihT [64][256]  @ 0       ([g*16+s][m*16+n], composed g0*g1 for ih)
//   A1hT  [64][256]  @ 16384   (same for hh)
//   C2ih  [64][256]  @ 32768   ([g*16+s][o*16+p], composed g2*g3 for ih)
//   C2h   [64][256]  @ 49152
//   biasS [4][256]   @ 65536   (ih_bias + hh_bias)
//   T2ih  [65536][64]@ 66560   (first-stage ih contraction for all rows)

#define WS_A1I 0
#define WS_A1H 16384
#define WS_C2I 32768
#define WS_C2H 49152
#define WS_BIAS 65536
#define WS_T2 66560

// Barrier draining LDS only (lgkmcnt), NOT global loads/stores (vmcnt):
// per-step out-store + T2 prefetch stay in flight across barriers.
__device__ __forceinline__ void bar_lds() {
    asm volatile("s_waitcnt lgkmcnt(0)\n\ts_barrier" ::: "memory");
}

// ---------------- K0: compose TT cores ----------------
__global__ void k_compose(const float* __restrict__ g0i, const float* __restrict__ g1i,
                          const float* __restrict__ g2i, const float* __restrict__ g3i,
                          const float* __restrict__ bi,
                          const float* __restrict__ g0h, const float* __restrict__ g1h,
                          const float* __restrict__ g2h, const float* __restrict__ g3h,
                          const float* __restrict__ bh,
                          float* __restrict__ ws) {
    int id = blockIdx.x * 256 + threadIdx.x;
    if (id < 16384) {
        int g = id >> 12, s = (id >> 8) & 15, mn = id & 255;
        int m = mn >> 4, n = mn & 15;
        float aI = 0.f, aH = 0.f;
        for (int r = 0; r < 16; ++r) {
            aI += g0i[(g * 16 + m) * 16 + r] * g1i[((g * 16 + r) * 16 + n) * 16 + s];
            aH += g0h[(g * 16 + m) * 16 + r] * g1h[((g * 16 + r) * 16 + n) * 16 + s];
        }
        ws[WS_A1I + (g * 16 + s) * 256 + mn] = aI;
        ws[WS_A1H + (g * 16 + s) * 256 + mn] = aH;
    } else if (id < 32768) {
        int id2 = id - 16384;
        int g = id2 >> 12, s = (id2 >> 8) & 15, j = id2 & 255;
        int o = j >> 4, p = j & 15;
        float aI = 0.f, aH = 0.f;
        for (int t = 0; t < 16; ++t) {
            aI += g2i[((g * 16 + s) * 16 + o) * 16 + t] * g3i[(g * 16 + t) * 16 + p];
            aH += g2h[((g * 16 + s) * 16 + o) * 16 + t] * g3h[(g * 16 + t) * 16 + p];
        }
        ws[WS_C2I + (g * 16 + s) * 256 + j] = aI;
        ws[WS_C2H + (g * 16 + s) * 256 + j] = aH;
    } else if (id < 33792) {
        int id2 = id - 32768;
        ws[WS_BIAS + id2] = bi[id2] + bh[id2];
    }
}

// ---------------- K1: T2ih = X @ A1ih ----------------
// Both tiles xor-swizzled by (row&15) on the f4-column -> conflict-free reads.
__global__ __launch_bounds__(256, 2) void k_t2ih(const float* __restrict__ x,
                                                 const float* __restrict__ ws,
                                                 float* __restrict__ T2) {
    __shared__ __align__(16) float Xs[64 * 256];
    __shared__ __align__(16) float As[64 * 256];
    const int tid = threadIdx.x;
    const long r0 = (long)blockIdx.x * 64;

    const float4* X4 = (const float4*)(x + r0 * 256);
    const float4* A4 = (const float4*)(ws + WS_A1I);
    float4* Xs4 = (float4*)Xs;
    float4* As4 = (float4*)As;
#pragma unroll
    for (int k = 0; k < 16; ++k) {
        int idx = tid + k * 256;
        int row = idx >> 6, c = idx & 63;
        int sw = (row << 6) | (c ^ (row & 15));
        Xs4[sw] = X4[idx];
        As4[sw] = A4[idx];
    }
    __syncthreads();

    const int ro = tid & 15;
    const int q  = tid >> 4;
    float acc[4][4];
#pragma unroll
    for (int i = 0; i < 4; ++i)
#pragma unroll
        for (int j = 0; j < 4; ++j) acc[i][j] = 0.f;

    for (int mn4 = 0; mn4 < 64; ++mn4) {
        float4 a[4], xv[4];
#pragma unroll
        for (int j = 0; j < 4; ++j) {
            int row = ro * 4 + j;
            a[j] = As4[(row << 6) | (mn4 ^ (row & 15))];
        }
#pragma unroll
        for (int i = 0; i < 4; ++i) {
            int row = q * 4 + i;
            xv[i] = Xs4[(row << 6) | (mn4 ^ (row & 15))];
        }
#pragma unroll
        for (int i = 0; i < 4; ++i)
#pragma unroll
            for (int j = 0; j < 4; ++j)
                acc[i][j] += xv[i].x * a[j].x + xv[i].y * a[j].y +
                             xv[i].z * a[j].z + xv[i].w * a[j].w;
    }
#pragma unroll
    for (int i = 0; i < 4; ++i)
#pragma unroll
        for (int j = 0; j < 4; ++j)
            T2[(r0 + q * 4 + i) * 64 + ro * 4 + j] = acc[i][j];
}

// ---------------- K2: recurrent LSTM ----------------
// 64 blocks x 1024 threads (16 waves, 4/SIMD), 1024 steps.
// TWO stages / TWO barriers / TWO LDS roundtrips per step (was 3):
//  AB  (all waves): u=4w+(lane>>4), sub=lane&15 -> a1r[16]; 16 FMA; reduce
//      over sub via shfl_xor(1,2,4,8); sub==0 lanes write t2hS[u].
//  CD+cell fused (all waves): wave w owns j in [16w,16w+16); lane=(g<<4)|jj.
//      32 FMA -> raw gate; unified activation act=1-m*rcp(1+exp2(1.4427*m*x))
//      (m=2 for tanh g==2, m=1 for sigmoid) -> NO divergence; 4 independent
//      __shfl gather i,f,g,o per jj; c,h computed redundantly in 4 lanes;
//      g==0 lanes write hS + out. No gS array, no third barrier.
__global__ __launch_bounds__(1024, 4) void k_lstm(const float* __restrict__ ws,
                                                  const float* __restrict__ T2,
                                                  float* __restrict__ out) {
    __shared__ __align__(16) float hS[256];
    __shared__ __align__(16) float t2hS[64];
    __shared__ __align__(16) float t2iS[2][64];

    const int tid  = threadIdx.x;
    const int w    = tid >> 6;
    const int lane = tid & 63;
    const int b    = blockIdx.x;

    // ---- AB weights: a1r[16] = A1h[u][sub*16 .. sub*16+16) ----
    const int uab = 4 * w + (lane >> 4);
    const int sub = lane & 15;
    float a1r[16];
    {
        const float4* A1h4 = (const float4*)(ws + WS_A1H);
#pragma unroll
        for (int kk = 0; kk < 4; ++kk) {
            float4 v = A1h4[uab * 64 + sub * 4 + kk];
            a1r[4 * kk + 0] = v.x; a1r[4 * kk + 1] = v.y;
            a1r[4 * kk + 2] = v.z; a1r[4 * kk + 3] = v.w;
        }
    }

    // ---- CD weights: gate g = lane>>4, hidden j = 16w + (lane&15) ----
    const int g  = lane >> 4;
    const int jj = lane & 15;
    const int j  = 16 * w + jj;
    float c2h[16], c2i[16];
#pragma unroll
    for (int s = 0; s < 16; ++s) {
        c2h[s] = ws[WS_C2H + (16 * g + s) * 256 + j];
        c2i[s] = ws[WS_C2I + (16 * g + s) * 256 + j];
    }
    float bias = ws[WS_BIAS + g * 256 + j];
    const float am = (g == 2) ? 2.0f : 1.0f;            // tanh vs sigmoid
    const float as = 1.442695040888963f * am;

#pragma unroll
    for (int i = 0; i < 16; ++i)
        asm volatile("" : "+v"(a1r[i]), "+v"(c2h[i]), "+v"(c2i[i]));

    float c = 0.f, h_last = 0.f;
    if (tid < 256) hS[tid] = 0.f;
    const float* T2b = T2 + (long)b * 1024 * 64;
    const float4* T2b4 = (const float4*)T2b;
    float4 preA = make_float4(0.f, 0.f, 0.f, 0.f);
    float4 preB = make_float4(0.f, 0.f, 0.f, 0.f);
    if (tid < 16) {
        ((float4*)t2iS[0])[tid] = T2b4[tid];
        preA = T2b4[16 + tid];                          // T2[t=1]
    }
    bar_lds();

    float* outB = out + (long)b * 1024 * 256;
    const float4* hS4 = (const float4*)hS;
    const float4* th4 = (const float4*)t2hS;

    auto body = [&](int t, float4& preW, float4& preL) {
        // ---- AB ----
        float4 s4 = make_float4(0.f, 0.f, 0.f, 0.f);
#pragma unroll
        for (int kk = 0; kk < 4; ++kk) {
            float4 hv = hS4[sub * 4 + kk];              // 2-way bcast, free
            s4.x += hv.x * a1r[4 * kk + 0];
            s4.y += hv.y * a1r[4 * kk + 1];
            s4.z += hv.z * a1r[4 * kk + 2];
            s4.w += hv.w * a1r[4 * kk + 3];
        }
        float tv = (s4.x + s4.y) + (s4.z + s4.w);
        // stage next t2i + prefetch while shfl chain runs
        if ((tid < 16) && (t + 1 < 1024))
            ((float4*)t2iS[(t + 1) & 1])[tid] = preW;   // other buffer: no race
        if ((tid < 16) && (t + 2 < 1024))
            preL = T2b4[(t + 2) * 16 + tid];
        tv += __shfl_xor(tv, 1);
        tv += __shfl_xor(tv, 2);
        tv += __shfl_xor(tv, 4);
        tv += __shfl_xor(tv, 8);
        if (sub == 0) t2hS[uab] = tv;

        bar_lds();  // 1: t2hS (and t2iS[(t+1)&1]) ready

        // ---- CD + cell ----
        const float4* ti4 = (const float4*)t2iS[t & 1];
        float acc = bias;
#pragma unroll
        for (int q = 0; q < 4; ++q) {
            float4 th = th4[g * 4 + q];                 // 4-addr bcast, free
            float4 ti = ti4[g * 4 + q];
            acc += th.x * c2h[4*q+0] + th.y * c2h[4*q+1] + th.z * c2h[4*q+2] + th.w * c2h[4*q+3]
                 + ti.x * c2i[4*q+0] + ti.y * c2i[4*q+1] + ti.z * c2i[4*q+2] + ti.w * c2i[4*q+3];
        }
        // unified activation: sigmoid(x)=1-1/(1+e^x), tanh(x)=1-2/(1+e^2x)
        float e   = __builtin_amdgcn_exp2f(as * acc);
        float act = 1.0f - am * __builtin_amdgcn_rcpf(1.0f + e);
        // gather i,f,g,o for this jj (4 independent in-wave permutes)
        float gi = __shfl(act, jj);
        float gf = __shfl(act, jj + 16);
        float gg = __shfl(act, jj + 32);
        float go = __shfl(act, jj + 48);
        c = gf * c + gi * gg;
        float e2 = __builtin_amdgcn_exp2f(2.885390081777926f * c);
        float th_ = 1.0f - 2.0f * __builtin_amdgcn_rcpf(1.0f + e2);
        float h = go * th_;
        h_last = h;
        if (g == 0) {
            hS[j] = h;
            outB[t * 256 + j] = h;                      // never drained (bar_lds)
        }

        bar_lds();  // 2: hS ready for next AB
    };

    for (int t = 0; t < 1024; t += 2) {
        body(t, preA, preB);
        body(t + 1, preB, preA);
    }

    if (g == 0) {
        out[16777216 + b * 256 + j] = h_last;
        out[16777216 + 16384 + b * 256 + j] = c;
    }
}

extern "C" void kernel_launch(void* const* d_in, const int* in_sizes, int n_in,
                              void* d_out, int out_size, void* d_ws, size_t ws_size,
                              hipStream_t stream) {
    const float* x     = (const float*)d_in[0];
    const float* ih_g0 = (const float*)d_in[1];
    const float* ih_g1 = (const float*)d_in[2];
    const float* ih_g2 = (const float*)d_in[3];
    const float* ih_g3 = (const float*)d_in[4];
    const float* ih_b  = (const float*)d_in[5];
    const float* hh_g0 = (const float*)d_in[6];
    const float* hh_g1 = (const float*)d_in[7];
    const float* hh_g2 = (const float*)d_in[8];
    const float* hh_g3 = (const float*)d_in[9];
    const float* hh_b  = (const float*)d_in[10];
    float* out = (float*)d_out;
    float* ws  = (float*)d_ws;

    k_compose<<<132, 256, 0, stream>>>(ih_g0, ih_g1, ih_g2, ih_g3, ih_b,
                                       hh_g0, hh_g1, hh_g2, hh_g3, hh_b, ws);
    k_t2ih<<<1024, 256, 0, stream>>>(x, ws, ws + WS_T2);
    k_lstm<<<64, 1024, 0, stream>>>(ws, ws + WS_T2, out);
}

// Round 8
// 920.366 us; speedup vs baseline: 2.9204x; 1.6800x over previous
//
#include <hip/hip_runtime.h>

// TT-LSTM: B=64, T=1024, D=H=256, F=16, R=16, NG=4.
// ws layout (floats):
//   A1ihT [64][256]  @ 0       ([g*16+s][m*16+n], composed g0*g1 for ih)
//   A1hT  [64][256]  @ 16384   (same for hh)
//   C2ih  [64][256]  @ 32768   ([g*16+s][o*16+p], composed g2*g3 for ih)
//   C2h   [64][256]  @ 49152
//   biasS [4][256]   @ 65536   (ih_bias + hh_bias)
//   T2ih  [65536][64]@ 66560   (first-stage ih contraction for all rows)

#define WS_A1I 0
#define WS_A1H 16384
#define WS_C2I 32768
#define WS_C2H 49152
#define WS_BIAS 65536
#define WS_T2 66560

// Barrier draining LDS only (lgkmcnt), NOT global loads/stores (vmcnt).
__device__ __forceinline__ void bar_lds() {
    asm volatile("s_waitcnt lgkmcnt(0)\n\ts_barrier" ::: "memory");
}

// DPP helpers: cross-lane at VALU rate (no DS pipe). dpp_ctrl must be an
// immediate -> template parameter (r7 compile fix).
// row_shr:n = 0x110|n ; quad_perm(k,k,k,k) = k*0x55. bound_ctrl=1 -> 0 fill.
template <int CTRL>
__device__ __forceinline__ float dpp_add(float v) {
    int s = __builtin_amdgcn_update_dpp(0, __float_as_int(v), CTRL, 0xF, 0xF, true);
    return v + __int_as_float(s);
}
template <int CTRL>
__device__ __forceinline__ float dpp_bcast(float v) {
    int s = __builtin_amdgcn_update_dpp(0, __float_as_int(v), CTRL, 0xF, 0xF, true);
    return __int_as_float(s);
}

// ---------------- K0: compose TT cores ----------------
__global__ void k_compose(const float* __restrict__ g0i, const float* __restrict__ g1i,
                          const float* __restrict__ g2i, const float* __restrict__ g3i,
                          const float* __restrict__ bi,
                          const float* __restrict__ g0h, const float* __restrict__ g1h,
                          const float* __restrict__ g2h, const float* __restrict__ g3h,
                          const float* __restrict__ bh,
                          float* __restrict__ ws) {
    int id = blockIdx.x * 256 + threadIdx.x;
    if (id < 16384) {
        int g = id >> 12, s = (id >> 8) & 15, mn = id & 255;
        int m = mn >> 4, n = mn & 15;
        float aI = 0.f, aH = 0.f;
        for (int r = 0; r < 16; ++r) {
            aI += g0i[(g * 16 + m) * 16 + r] * g1i[((g * 16 + r) * 16 + n) * 16 + s];
            aH += g0h[(g * 16 + m) * 16 + r] * g1h[((g * 16 + r) * 16 + n) * 16 + s];
        }
        ws[WS_A1I + (g * 16 + s) * 256 + mn] = aI;
        ws[WS_A1H + (g * 16 + s) * 256 + mn] = aH;
    } else if (id < 32768) {
        int id2 = id - 16384;
        int g = id2 >> 12, s = (id2 >> 8) & 15, j = id2 & 255;
        int o = j >> 4, p = j & 15;
        float aI = 0.f, aH = 0.f;
        for (int t = 0; t < 16; ++t) {
            aI += g2i[((g * 16 + s) * 16 + o) * 16 + t] * g3i[(g * 16 + t) * 16 + p];
            aH += g2h[((g * 16 + s) * 16 + o) * 16 + t] * g3h[(g * 16 + t) * 16 + p];
        }
        ws[WS_C2I + (g * 16 + s) * 256 + j] = aI;
        ws[WS_C2H + (g * 16 + s) * 256 + j] = aH;
    } else if (id < 33792) {
        int id2 = id - 32768;
        ws[WS_BIAS + id2] = bi[id2] + bh[id2];
    }
}

// ---------------- K1: T2ih = X @ A1ih ----------------
__global__ __launch_bounds__(256, 2) void k_t2ih(const float* __restrict__ x,
                                                 const float* __restrict__ ws,
                                                 float* __restrict__ T2) {
    __shared__ __align__(16) float Xs[64 * 256];
    __shared__ __align__(16) float As[64 * 256];
    const int tid = threadIdx.x;
    const long r0 = (long)blockIdx.x * 64;

    const float4* X4 = (const float4*)(x + r0 * 256);
    const float4* A4 = (const float4*)(ws + WS_A1I);
    float4* Xs4 = (float4*)Xs;
    float4* As4 = (float4*)As;
#pragma unroll
    for (int k = 0; k < 16; ++k) {
        int idx = tid + k * 256;
        int row = idx >> 6, c = idx & 63;
        int sw = (row << 6) | (c ^ (row & 15));
        Xs4[sw] = X4[idx];
        As4[sw] = A4[idx];
    }
    __syncthreads();

    const int ro = tid & 15;
    const int q  = tid >> 4;
    float acc[4][4];
#pragma unroll
    for (int i = 0; i < 4; ++i)
#pragma unroll
        for (int j = 0; j < 4; ++j) acc[i][j] = 0.f;

    for (int mn4 = 0; mn4 < 64; ++mn4) {
        float4 a[4], xv[4];
#pragma unroll
        for (int j = 0; j < 4; ++j) {
            int row = ro * 4 + j;
            a[j] = As4[(row << 6) | (mn4 ^ (row & 15))];
        }
#pragma unroll
        for (int i = 0; i < 4; ++i) {
            int row = q * 4 + i;
            xv[i] = Xs4[(row << 6) | (mn4 ^ (row & 15))];
        }
#pragma unroll
        for (int i = 0; i < 4; ++i)
#pragma unroll
            for (int j = 0; j < 4; ++j)
                acc[i][j] += xv[i].x * a[j].x + xv[i].y * a[j].y +
                             xv[i].z * a[j].z + xv[i].w * a[j].w;
    }
#pragma unroll
    for (int i = 0; i < 4; ++i)
#pragma unroll
        for (int j = 0; j < 4; ++j)
            T2[(r0 + q * 4 + i) * 64 + ro * 4 + j] = acc[i][j];
}

// ---------------- K2: recurrent LSTM ----------------
// 64 blocks x 1024 threads (16 waves, 4/SIMD), 1024 steps, 2 barriers/step.
// ZERO DS-pipe cross-lane ops: reductions/gathers via DPP (VALU rate).
//  AB: u=4w+(lane>>4), sub=lane&15 -> a1r[16]; 16 FMA; DPP row_shr 1/2/4/8
//      sum over sub (result in sub==15); that lane writes t2hS[u].
//  CD+cell: jj=lane>>2, g=lane&3, j=16w+jj. 32 FMA; unified activation
//      (m=2 tanh / m=1 sigmoid, no divergence); DPP quad_perm broadcasts
//      gather i,f,g,o within the quad; g==0 lane writes hS + out.
// hS transposed layout: float4 slot kk*16+sub = h[16*sub+4*kk .. +3]
// -> AB reads bank-base 4*sub mod 32 = true 2-way (free). r6's sub*4+kk
// layout was 8-way conflicted (5e7 conflicts) - that + 8 ds_bpermute/step
// was the r6 regression.
__global__ __launch_bounds__(1024, 4) void k_lstm(const float* __restrict__ ws,
                                                  const float* __restrict__ T2,
                                                  float* __restrict__ out) {
    __shared__ __align__(16) float hS[256];
    __shared__ __align__(16) float t2hS[64];
    __shared__ __align__(16) float t2iS[2][64];

    const int tid  = threadIdx.x;
    const int w    = tid >> 6;
    const int lane = tid & 63;
    const int b    = blockIdx.x;

    // ---- AB weights: a1r[16] = A1h[u][sub*16 .. sub*16+16) ----
    const int uab = 4 * w + (lane >> 4);
    const int sub = lane & 15;
    float a1r[16];
    {
        const float4* A1h4 = (const float4*)(ws + WS_A1H);
#pragma unroll
        for (int kk = 0; kk < 4; ++kk) {
            float4 v = A1h4[uab * 64 + sub * 4 + kk];
            a1r[4 * kk + 0] = v.x; a1r[4 * kk + 1] = v.y;
            a1r[4 * kk + 2] = v.z; a1r[4 * kk + 3] = v.w;
        }
    }

    // ---- CD weights: jj=lane>>2, gate g=lane&3, hidden j=16w+jj ----
    const int jj = lane >> 2;
    const int g  = lane & 3;
    const int j  = 16 * w + jj;
    float c2h[16], c2i[16];
#pragma unroll
    for (int s = 0; s < 16; ++s) {
        c2h[s] = ws[WS_C2H + (16 * g + s) * 256 + j];
        c2i[s] = ws[WS_C2I + (16 * g + s) * 256 + j];
    }
    float bias = ws[WS_BIAS + g * 256 + j];
    const float am = (g == 2) ? 2.0f : 1.0f;            // tanh vs sigmoid
    const float as = 1.442695040888963f * am;

#pragma unroll
    for (int i = 0; i < 16; ++i)
        asm volatile("" : "+v"(a1r[i]), "+v"(c2h[i]), "+v"(c2i[i]));

    // transposed hS slot for writer (g==0): word 64*(jj>>2) + 4*w + (jj&3)
    const int hw = ((jj >> 2) << 6) + (w << 2) + (jj & 3);

    float c = 0.f, h_last = 0.f;
    if (tid < 256) hS[tid] = 0.f;
    const float* T2b = T2 + (long)b * 1024 * 64;
    const float4* T2b4 = (const float4*)T2b;
    float4 preA = make_float4(0.f, 0.f, 0.f, 0.f);
    float4 preB = make_float4(0.f, 0.f, 0.f, 0.f);
    if (tid < 16) {
        ((float4*)t2iS[0])[tid] = T2b4[tid];
        preA = T2b4[16 + tid];                          // T2[t=1]
    }
    bar_lds();

    float* outB = out + (long)b * 1024 * 256;
    const float4* hS4 = (const float4*)hS;
    const float4* th4 = (const float4*)t2hS;

    auto body = [&](int t, float4& preW, float4& preL) {
        // ---- AB ----
        float4 s4 = make_float4(0.f, 0.f, 0.f, 0.f);
#pragma unroll
        for (int kk = 0; kk < 4; ++kk) {
            float4 hv = hS4[kk * 16 + sub];             // 2-way bcast, free
            s4.x += hv.x * a1r[4 * kk + 0];
            s4.y += hv.y * a1r[4 * kk + 1];
            s4.z += hv.z * a1r[4 * kk + 2];
            s4.w += hv.w * a1r[4 * kk + 3];
        }
        float tv = (s4.x + s4.y) + (s4.z + s4.w);
        // stage next t2i + prefetch (independent; overlaps DPP chain)
        if ((tid < 16) && (t + 1 < 1024))
            ((float4*)t2iS[(t + 1) & 1])[tid] = preW;
        if ((tid < 16) && (t + 2 < 1024))
            preL = T2b4[(t + 2) * 16 + tid];
        // DPP sum over 16-lane row -> total in sub==15 (VALU rate)
        tv = dpp_add<0x111>(tv);   // row_shr:1
        tv = dpp_add<0x112>(tv);   // row_shr:2
        tv = dpp_add<0x114>(tv);   // row_shr:4
        tv = dpp_add<0x118>(tv);   // row_shr:8
        if (sub == 15) t2hS[uab] = tv;

        bar_lds();  // 1: t2hS + t2iS[(t+1)&1] ready

        // ---- CD + cell ----
        const float4* ti4 = (const float4*)t2iS[t & 1];
        float acc = bias;
#pragma unroll
        for (int q = 0; q < 4; ++q) {
            float4 th = th4[g * 4 + q];                 // 2-way bcast, free
            float4 ti = ti4[g * 4 + q];
            acc += th.x * c2h[4*q+0] + th.y * c2h[4*q+1] + th.z * c2h[4*q+2] + th.w * c2h[4*q+3]
                 + ti.x * c2i[4*q+0] + ti.y * c2i[4*q+1] + ti.z * c2i[4*q+2] + ti.w * c2i[4*q+3];
        }
        // unified activation: sigmoid(x)=1-1/(1+e^x), tanh(x)=1-2/(1+e^2x)
        float e   = __builtin_amdgcn_exp2f(as * acc);
        float act = 1.0f - am * __builtin_amdgcn_rcpf(1.0f + e);
        // gather i,f,g,o within the quad via DPP broadcasts
        float gi = dpp_bcast<0x00>(act);
        float gf = dpp_bcast<0x55>(act);
        float gg = dpp_bcast<0xAA>(act);
        float go = dpp_bcast<0xFF>(act);
        c = gf * c + gi * gg;
        float e2 = __builtin_amdgcn_exp2f(2.885390081777926f * c);
        float th_ = 1.0f - 2.0f * __builtin_amdgcn_rcpf(1.0f + e2);
        float h = go * th_;
        h_last = h;
        if (g == 0) {
            hS[hw] = h;                                 // 4-way write, ~free
            outB[t * 256 + j] = h;                      // never drained
        }

        bar_lds();  // 2: hS ready for next AB
    };

    for (int t = 0; t < 1024; t += 2) {
        body(t, preA, preB);
        body(t + 1, preB, preA);
    }

    if (g == 0) {
        out[16777216 + b * 256 + j] = h_last;
        out[16777216 + 16384 + b * 256 + j] = c;
    }
}

extern "C" void kernel_launch(void* const* d_in, const int* in_sizes, int n_in,
                              void* d_out, int out_size, void* d_ws, size_t ws_size,
                              hipStream_t stream) {
    const float* x     = (const float*)d_in[0];
    const float* ih_g0 = (const float*)d_in[1];
    const float* ih_g1 = (const float*)d_in[2];
    const float* ih_g2 = (const float*)d_in[3];
    const float* ih_g3 = (const float*)d_in[4];
    const float* ih_b  = (const float*)d_in[5];
    const float* hh_g0 = (const float*)d_in[6];
    const float* hh_g1 = (const float*)d_in[7];
    const float* hh_g2 = (const float*)d_in[8];
    const float* hh_g3 = (const float*)d_in[9];
    const float* hh_b  = (const float*)d_in[10];
    float* out = (float*)d_out;
    float* ws  = (float*)d_ws;

    k_compose<<<132, 256, 0, stream>>>(ih_g0, ih_g1, ih_g2, ih_g3, ih_b,
                                       hh_g0, hh_g1, hh_g2, hh_g3, hh_b, ws);
    k_t2ih<<<1024, 256, 0, stream>>>(x, ws, ws + WS_T2);
    k_lstm<<<64, 1024, 0, stream>>>(ws, ws + WS_T2, out);
}